// Round 3
// baseline (24235.150 us; speedup 1.0000x reference)
//
#include <hip/hip_runtime.h>
#include <math.h>

// Round 3: same arithmetic DAG as the round-2 passing kernel for every chain
// that feeds a softmax (projections, kq, kq64, kq2, softmaxes). Changes:
//  - k stored TRANSPOSED kT[s][i] (stride 132, aligned) -> kq reads k via
//    broadcast ds_read_b128 (4 i per instr); same for q2T in stage 2.
//  - pre1 reads att via broadcast b128; att2/pre2 use float4 chains.
//  - pre2 and L3 (post-softmax, reassociation-safe) parallelized across all
//    1024 threads with split-K partials + ordered LDS reduction.

__global__ __launch_bounds__(1024)
void literal_kernel(const float* __restrict__ in0,
                    const float* __restrict__ emb,
                    const float* __restrict__ wk11, const float* __restrict__ wq11,
                    const float* __restrict__ wv11,
                    const float* __restrict__ wk12, const float* __restrict__ wq12,
                    const float* __restrict__ wv12,
                    const float* __restrict__ l1,
                    const float* __restrict__ wk21, const float* __restrict__ wq21,
                    const float* __restrict__ wv21,
                    const float* __restrict__ wk22, const float* __restrict__ wq22,
                    const float* __restrict__ wv22,
                    const float* __restrict__ l2,
                    const float* __restrict__ L3, const float* __restrict__ L4,
                    float* __restrict__ out)
{
    __shared__ float xsh[66];
    __shared__ float ysh[128 * 65];                 // y[j][s]; later y2[h][s]
    __shared__ __align__(16) float kTsh[65 * 132];  // kT[s][i]; att[s*128+i]; q2T[t][i]
    __shared__ float qsh[128 * 65];                 // q[i][t]
    __shared__ __align__(16) float vsh[128 * 68];   // v[i][t] / v2[i][t], stride 68
    __shared__ __align__(16) float smsh[65 * 68];   // sm[s][t] stride 68; stage2: psum/l3p
    __shared__ float kq64sh[65];
    __shared__ __align__(16) float k2col[128];
    __shared__ __align__(16) float attr[128];
    __shared__ float lshf[66];
    __shared__ __align__(16) float smr[68];
    __shared__ float y4sh[128];

    const int tid  = threadIdx.x;
    const int lane = tid & 63;
    const int wu   = __builtin_amdgcn_readfirstlane(tid >> 6);   // wave 0..15
    const long b   = blockIdx.x;

    if (tid < 64) xsh[tid] = in0[b * 64 + tid];
    if (tid == 64) xsh[64] = 1.0f;
    __syncthreads();

    // y[j][s] = emb[j][s] * x[s]
    for (int idx = tid; idx < 8320; idx += 1024) {
        int s = idx % 65;
        ysh[idx] = emb[idx] * xsh[s];
    }
    __syncthreads();

    // pre1 accumulators: thread owns h = 4*(tid&31)..+3, s = (tid>>5) + 32*si
    const int h4 = (tid & 31) * 4;
    const int sb = tid >> 5;            // 0..31
    float4 acc1[3];
    acc1[0] = make_float4(0.f, 0.f, 0.f, 0.f);
    acc1[1] = make_float4(0.f, 0.f, 0.f, 0.f);
    acc1[2] = make_float4(0.f, 0.f, 0.f, 0.f);

    float* attsh = kTsh;   // att[s*128+i] overwrites kT after kq

    for (int a = 0; a < 2; ++a) {
        const float* wk = a ? wk12 : wk11;
        const float* wq = a ? wq12 : wq11;
        const float* wv = a ? wv12 : wv11;

        // ---- projections: wave wu computes rows i = wu*8 + r, lanes = col s ----
        {
            float aK[8], aQ[8], aV[8];
            #pragma unroll
            for (int r = 0; r < 8; ++r) { aK[r] = aQ[r] = aV[r] = 0.f; }
            float acc64 = 0.f;                       // col-64 side chain (24 lanes)
            const int i0 = wu * 8;
            const int ch = lane >> 3;                // 0:K 1:Q 2:V for lane<24
            const float* Wc = (ch == 0) ? wk : ((ch == 1) ? wq : wv);
            const float* wcrow = Wc + (i0 + (lane & 7)) * 128;

            for (int jb = 0; jb < 16; ++jb) {
                float yv[8], y64v[8];
                #pragma unroll
                for (int u = 0; u < 8; ++u) {
                    yv[u]   = ysh[(jb * 8 + u) * 65 + lane];
                    y64v[u] = ysh[(jb * 8 + u) * 65 + 64];
                }
                #pragma unroll
                for (int r = 0; r < 8; ++r) {
                    const float* wkr = wk + (i0 + r) * 128 + jb * 8;
                    const float* wqr = wq + (i0 + r) * 128 + jb * 8;
                    const float* wvr = wv + (i0 + r) * 128 + jb * 8;
                    #pragma unroll
                    for (int u = 0; u < 8; ++u) {
                        aK[r] = fmaf(wkr[u], yv[u], aK[r]);
                        aQ[r] = fmaf(wqr[u], yv[u], aQ[r]);
                        aV[r] = fmaf(wvr[u], yv[u], aV[r]);
                    }
                }
                if (lane < 24) {
                    float4 c0 = *(const float4*)&wcrow[jb * 8];
                    float4 c1 = *(const float4*)&wcrow[jb * 8 + 4];
                    acc64 = fmaf(c0.x, y64v[0], acc64);
                    acc64 = fmaf(c0.y, y64v[1], acc64);
                    acc64 = fmaf(c0.z, y64v[2], acc64);
                    acc64 = fmaf(c0.w, y64v[3], acc64);
                    acc64 = fmaf(c1.x, y64v[4], acc64);
                    acc64 = fmaf(c1.y, y64v[5], acc64);
                    acc64 = fmaf(c1.z, y64v[6], acc64);
                    acc64 = fmaf(c1.w, y64v[7], acc64);
                }
            }
            #pragma unroll
            for (int r = 0; r < 8; ++r) {
                int i = i0 + r;
                kTsh[lane * 132 + i] = aK[r];        // transposed
                qsh[i * 65 + lane] = aQ[r];
                vsh[i * 68 + lane] = aV[r];
            }
            if (lane < 8)       kTsh[64 * 132 + i0 + lane]       = acc64;
            else if (lane < 16) qsh[(i0 + (lane & 7)) * 65 + 64] = acc64;
            else if (lane < 24) vsh[(i0 + (lane & 7)) * 68 + 64] = acc64;
        }
        __syncthreads();

        // ---- kq: wave wu owns rows s = 4*wu + rr (wave 15 also s=64) ----
        float kqa[5];
        kqa[0] = kqa[1] = kqa[2] = kqa[3] = kqa[4] = 0.f;
        if (tid < 65) {                       // column t = 64 (exact chain)
            float acc = 0.f;
            const float* kr = &kTsh[tid * 132];
            for (int i0b = 0; i0b < 128; i0b += 4) {
                float4 kk = *(const float4*)&kr[i0b];
                acc = fmaf(kk.x, qsh[(i0b + 0) * 65 + 64], acc);
                acc = fmaf(kk.y, qsh[(i0b + 1) * 65 + 64], acc);
                acc = fmaf(kk.z, qsh[(i0b + 2) * 65 + 64], acc);
                acc = fmaf(kk.w, qsh[(i0b + 3) * 65 + 64], acc);
            }
            kq64sh[tid] = acc;
        }
        {
            const int sbase = 4 * wu;
            for (int i0b = 0; i0b < 128; i0b += 4) {
                float4 k0 = *(const float4*)&kTsh[(sbase + 0) * 132 + i0b];
                float4 k1 = *(const float4*)&kTsh[(sbase + 1) * 132 + i0b];
                float4 k2 = *(const float4*)&kTsh[(sbase + 2) * 132 + i0b];
                float4 k3 = *(const float4*)&kTsh[(sbase + 3) * 132 + i0b];
                float q0 = qsh[(i0b + 0) * 65 + lane];
                float q1 = qsh[(i0b + 1) * 65 + lane];
                float q2v = qsh[(i0b + 2) * 65 + lane];
                float q3v = qsh[(i0b + 3) * 65 + lane];
                kqa[0] = fmaf(k0.x, q0, kqa[0]); kqa[0] = fmaf(k0.y, q1, kqa[0]);
                kqa[0] = fmaf(k0.z, q2v, kqa[0]); kqa[0] = fmaf(k0.w, q3v, kqa[0]);
                kqa[1] = fmaf(k1.x, q0, kqa[1]); kqa[1] = fmaf(k1.y, q1, kqa[1]);
                kqa[1] = fmaf(k1.z, q2v, kqa[1]); kqa[1] = fmaf(k1.w, q3v, kqa[1]);
                kqa[2] = fmaf(k2.x, q0, kqa[2]); kqa[2] = fmaf(k2.y, q1, kqa[2]);
                kqa[2] = fmaf(k2.z, q2v, kqa[2]); kqa[2] = fmaf(k2.w, q3v, kqa[2]);
                kqa[3] = fmaf(k3.x, q0, kqa[3]); kqa[3] = fmaf(k3.y, q1, kqa[3]);
                kqa[3] = fmaf(k3.z, q2v, kqa[3]); kqa[3] = fmaf(k3.w, q3v, kqa[3]);
                if (wu == 15) {
                    float4 k4 = *(const float4*)&kTsh[64 * 132 + i0b];
                    kqa[4] = fmaf(k4.x, q0, kqa[4]); kqa[4] = fmaf(k4.y, q1, kqa[4]);
                    kqa[4] = fmaf(k4.z, q2v, kqa[4]); kqa[4] = fmaf(k4.w, q3v, kqa[4]);
                }
            }
        }
        __syncthreads();

        // ---- softmax over t, rows in registers (same butterfly DAG) ----
        #pragma unroll
        for (int rr = 0; rr < 5; ++rr) {
            if (rr < 4 || wu == 15) {
                int s = (rr == 4) ? 64 : 4 * wu + rr;
                float lg   = kqa[rr];
                float l64v = (lane == 0) ? kq64sh[s] : -3.0e38f;
                float mm = fmaxf(lg, l64v);
                #pragma unroll
                for (int off = 32; off >= 1; off >>= 1) mm = fmaxf(mm, __shfl_xor(mm, off));
                float e   = expf(lg - mm);
                float e64 = (lane == 0) ? expf(l64v - mm) : 0.f;
                float zs = e + e64;
                #pragma unroll
                for (int off = 32; off >= 1; off >>= 1) zs += __shfl_xor(zs, off);
                float inv = 1.0f / zs;
                smsh[s * 68 + lane] = e * inv;
                if (lane == 0) smsh[s * 68 + 64] = e64 * inv;
            }
        }
        __syncthreads();

        // ---- att[s][i] = sum_t sm[s][t]*v[i][t]; float4 along t ----
        {
            const int iA = tid & 127;
            const int sg = tid >> 7;           // 0..7, uniform per wave
            float aa[9];
            #pragma unroll
            for (int m = 0; m < 9; ++m) aa[m] = 0.f;
            for (int k = 0; k < 16; ++k) {
                float4 vq = *(const float4*)&vsh[iA * 68 + 4 * k];
                #pragma unroll
                for (int m = 0; m < 9; ++m) {
                    if (m < 8 || sg == 0) {
                        int s = sg + 8 * m;
                        float4 sq = *(const float4*)&smsh[s * 68 + 4 * k];
                        aa[m] = fmaf(sq.x, vq.x, aa[m]);
                        aa[m] = fmaf(sq.y, vq.y, aa[m]);
                        aa[m] = fmaf(sq.z, vq.z, aa[m]);
                        aa[m] = fmaf(sq.w, vq.w, aa[m]);
                    }
                }
            }
            float v64 = vsh[iA * 68 + 64];
            #pragma unroll
            for (int m = 0; m < 9; ++m) {
                if (m < 8 || sg == 0) {
                    int s = sg + 8 * m;
                    aa[m] = fmaf(smsh[s * 68 + 64], v64, aa[m]);
                    attsh[s * 128 + iA] = aa[m];
                }
            }
        }
        __syncthreads();

        // ---- pre1[s][h] += sum_i att[s][i]*l1a[i][h]  (b128 att broadcasts) ----
        {
            const float* l1a = l1 + a * (128 * 128);
            for (int i0b = 0; i0b < 128; i0b += 4) {
                float4 lv0 = *(const float4*)&l1a[(i0b + 0) * 128 + h4];
                float4 lv1 = *(const float4*)&l1a[(i0b + 1) * 128 + h4];
                float4 lv2 = *(const float4*)&l1a[(i0b + 2) * 128 + h4];
                float4 lv3 = *(const float4*)&l1a[(i0b + 3) * 128 + h4];
                #pragma unroll
                for (int si = 0; si < 3; ++si) {
                    if (si < 2 || sb == 0) {
                        int s = sb + 32 * si;
                        float4 av = *(const float4*)&attsh[s * 128 + i0b];
                        float4 acc = acc1[si];
                        acc.x = fmaf(av.x, lv0.x, acc.x); acc.x = fmaf(av.y, lv1.x, acc.x);
                        acc.x = fmaf(av.z, lv2.x, acc.x); acc.x = fmaf(av.w, lv3.x, acc.x);
                        acc.y = fmaf(av.x, lv0.y, acc.y); acc.y = fmaf(av.y, lv1.y, acc.y);
                        acc.y = fmaf(av.z, lv2.y, acc.y); acc.y = fmaf(av.w, lv3.y, acc.y);
                        acc.z = fmaf(av.x, lv0.z, acc.z); acc.z = fmaf(av.y, lv1.z, acc.z);
                        acc.z = fmaf(av.z, lv2.z, acc.z); acc.z = fmaf(av.w, lv3.z, acc.z);
                        acc.w = fmaf(av.x, lv0.w, acc.w); acc.w = fmaf(av.y, lv1.w, acc.w);
                        acc.w = fmaf(av.z, lv2.w, acc.w); acc.w = fmaf(av.w, lv3.w, acc.w);
                        acc1[si] = acc;
                    }
                }
            }
        }
        __syncthreads();
    }

    // ---- y2[h][s] = tanh(pre1[s][h])  (into ysh region, stride 65) ----
    float* y2sh = ysh;
    #pragma unroll
    for (int si = 0; si < 3; ++si) {
        if (si < 2 || sb == 0) {
            int s = sb + 32 * si;
            y2sh[(h4 + 0) * 65 + s] = tanhf(acc1[si].x);
            y2sh[(h4 + 1) * 65 + s] = tanhf(acc1[si].y);
            y2sh[(h4 + 2) * 65 + s] = tanhf(acc1[si].z);
            y2sh[(h4 + 3) * 65 + s] = tanhf(acc1[si].w);
        }
    }
    __syncthreads();

    // ---- stage 2 (literal; only row s=64 used downstream) ----
    float* q2Tsh = kTsh;        // q2T[t][i], stride 132
    float* v2sh  = vsh;         // stride 68
    float* psum  = smsh;        // stage-2 scratch (sm dead)
    float pre2 = 0.f;           // valid for tid < 128

    for (int a2 = 0; a2 < 2; ++a2) {
        const float* wk2 = a2 ? wk22 : wk21;
        const float* wq2 = a2 ? wq22 : wq21;
        const float* wv2 = a2 ? wv22 : wv21;

        {
            float aQ[8], aV[8];
            #pragma unroll
            for (int r = 0; r < 8; ++r) { aQ[r] = aV[r] = 0.f; }
            float acc64 = 0.f;               // 0..7: q2 col64, 8..15: v2 col64, 16..23: k2col
            const int i0 = wu * 8;
            const int ch = lane >> 3;
            const float* Wc = (ch == 0) ? wq2 : ((ch == 1) ? wv2 : wk2);
            const float* wcrow = Wc + (i0 + (lane & 7)) * 128;

            for (int jb = 0; jb < 16; ++jb) {
                float yv[8], y64v[8];
                #pragma unroll
                for (int u = 0; u < 8; ++u) {
                    yv[u]   = y2sh[(jb * 8 + u) * 65 + lane];
                    y64v[u] = y2sh[(jb * 8 + u) * 65 + 64];
                }
                #pragma unroll
                for (int r = 0; r < 8; ++r) {
                    const float* wqr = wq2 + (i0 + r) * 128 + jb * 8;
                    const float* wvr = wv2 + (i0 + r) * 128 + jb * 8;
                    #pragma unroll
                    for (int u = 0; u < 8; ++u) {
                        aQ[r] = fmaf(wqr[u], yv[u], aQ[r]);
                        aV[r] = fmaf(wvr[u], yv[u], aV[r]);
                    }
                }
                if (lane < 24) {
                    float4 c0 = *(const float4*)&wcrow[jb * 8];
                    float4 c1 = *(const float4*)&wcrow[jb * 8 + 4];
                    acc64 = fmaf(c0.x, y64v[0], acc64);
                    acc64 = fmaf(c0.y, y64v[1], acc64);
                    acc64 = fmaf(c0.z, y64v[2], acc64);
                    acc64 = fmaf(c0.w, y64v[3], acc64);
                    acc64 = fmaf(c1.x, y64v[4], acc64);
                    acc64 = fmaf(c1.y, y64v[5], acc64);
                    acc64 = fmaf(c1.z, y64v[6], acc64);
                    acc64 = fmaf(c1.w, y64v[7], acc64);
                }
            }
            #pragma unroll
            for (int r = 0; r < 8; ++r) {
                int i = i0 + r;
                q2Tsh[lane * 132 + i] = aQ[r];       // transposed
                v2sh[i * 68 + lane] = aV[r];
            }
            if (lane < 8)       q2Tsh[64 * 132 + i0 + lane]      = acc64;
            else if (lane < 16) v2sh[(i0 + (lane & 7)) * 68 + 64] = acc64;
            else if (lane < 24) k2col[i0 + (lane & 7)]            = acc64;
        }
        __syncthreads();

        // kq2[64][t] = sum_i k2col[i]*q2[i][t]  (exact i-ascending chain)
        if (tid < 65) {
            float acc = 0.f;
            const float* qr = &q2Tsh[tid * 132];
            for (int i0b = 0; i0b < 128; i0b += 4) {
                float4 qq = *(const float4*)&qr[i0b];
                float4 kc = *(const float4*)&k2col[i0b];
                acc = fmaf(kc.x, qq.x, acc);
                acc = fmaf(kc.y, qq.y, acc);
                acc = fmaf(kc.z, qq.z, acc);
                acc = fmaf(kc.w, qq.w, acc);
            }
            lshf[tid] = acc;
        }
        __syncthreads();

        if (tid < 64) {
            float lg   = lshf[lane];
            float l64v = (lane == 0) ? lshf[64] : -3.0e38f;
            float mm = fmaxf(lg, l64v);
            #pragma unroll
            for (int off = 32; off >= 1; off >>= 1) mm = fmaxf(mm, __shfl_xor(mm, off));
            float e   = expf(lg - mm);
            float e64 = (lane == 0) ? expf(l64v - mm) : 0.f;
            float zs = e + e64;
            #pragma unroll
            for (int off = 32; off >= 1; off >>= 1) zs += __shfl_xor(zs, off);
            float inv = 1.0f / zs;
            smr[lane] = e * inv;
            if (lane == 0) smr[64] = e64 * inv;
        }
        __syncthreads();

        // att2[64][i] = sum_t sm2[t]*v2[i][t]  (exact t-ascending chain)
        if (tid < 128) {
            float acc = 0.f;
            const float* vr = &v2sh[tid * 68];
            for (int k = 0; k < 16; ++k) {
                float4 sq = *(const float4*)&smr[4 * k];
                float4 vq = *(const float4*)&vr[4 * k];
                acc = fmaf(sq.x, vq.x, acc);
                acc = fmaf(sq.y, vq.y, acc);
                acc = fmaf(sq.z, vq.z, acc);
                acc = fmaf(sq.w, vq.w, acc);
            }
            acc = fmaf(smr[64], vr[64], acc);
            attr[tid] = acc;
        }
        __syncthreads();

        // pre2[h] += sum_i att2[i]*l2a[i][h]  (split-K over 8 chunks, post-softmax)
        {
            const int hh = tid & 127, cc = tid >> 7;
            const float* l2a = l2 + a2 * (128 * 128);
            float p = 0.f;
            #pragma unroll
            for (int g = 0; g < 4; ++g) {
                int i = cc * 16 + 4 * g;
                float4 av = *(const float4*)&attr[i];
                p = fmaf(av.x, l2a[(i + 0) * 128 + hh], p);
                p = fmaf(av.y, l2a[(i + 1) * 128 + hh], p);
                p = fmaf(av.z, l2a[(i + 2) * 128 + hh], p);
                p = fmaf(av.w, l2a[(i + 3) * 128 + hh], p);
            }
            psum[cc * 128 + hh] = p;
        }
        __syncthreads();
        if (tid < 128) {
            float red = psum[tid];
            #pragma unroll
            for (int c = 1; c < 8; ++c) red += psum[c * 128 + tid];
            pre2 += red;
        }
        // no barrier needed: psum not rewritten until after next a2's att2 sync
    }

    if (tid < 128) y4sh[tid] = tanhf(pre2);
    __syncthreads();

    // t3[o] = sum_h y4[h]*L3[h][o]  (split-K over 16 chunks, post-softmax)
    {
        float* l3p = smsh + 1024;
        const int oo = tid & 63, cc = tid >> 6;   // cc 0..15
        float p = 0.f;
        #pragma unroll
        for (int u = 0; u < 8; ++u) {
            int h = cc * 8 + u;
            p = fmaf(y4sh[h], L3[h * 64 + oo], p);
        }
        l3p[cc * 64 + oo] = p;
    }
    __syncthreads();
    if (tid < 64) {
        float* l3p = smsh + 1024;
        float t3 = l3p[tid];
        #pragma unroll
        for (int c = 1; c < 16; ++c) t3 += l3p[c * 64 + tid];
        float y5 = tanhf(t3);
        float sc = y5 * L4[tid];
        #pragma unroll
        for (int off = 32; off >= 1; off >>= 1) sc += __shfl_xor(sc, off);
        if (tid == 0) out[b] = sc;
    }
}

extern "C" void kernel_launch(void* const* d_in, const int* in_sizes, int n_in,
                              void* d_out, int out_size, void* d_ws, size_t ws_size,
                              hipStream_t stream) {
    const float* in0  = (const float*)d_in[0];
    const float* emb  = (const float*)d_in[1];
    const float* wk11 = (const float*)d_in[2];
    const float* wq11 = (const float*)d_in[3];
    const float* wv11 = (const float*)d_in[4];
    const float* wk12 = (const float*)d_in[5];
    const float* wq12 = (const float*)d_in[6];
    const float* wv12 = (const float*)d_in[7];
    const float* l1   = (const float*)d_in[8];
    const float* wk21 = (const float*)d_in[9];
    const float* wq21 = (const float*)d_in[10];
    const float* wv21 = (const float*)d_in[11];
    const float* wk22 = (const float*)d_in[12];
    const float* wq22 = (const float*)d_in[13];
    const float* wv22 = (const float*)d_in[14];
    const float* l2   = (const float*)d_in[15];
    const float* l3   = (const float*)d_in[16];
    const float* l4   = (const float*)d_in[17];
    float* out = (float*)d_out;

    int B = in_sizes[0] / 64;   // 8192

    literal_kernel<<<B, 1024, 0, stream>>>(in0, emb,
                                           wk11, wq11, wv11, wk12, wq12, wv12, l1,
                                           wk21, wq21, wv21, wk22, wq22, wv22, l2,
                                           l3, l4, out);
}

// Round 4
// 24212.338 us; speedup vs baseline: 1.0009x; 1.0009x over previous
//
#include <hip/hip_runtime.h>
#include <math.h>

// Round 4 = round 3 body, byte-identical, with __launch_bounds__(1024, 4).
// Round 3 spilled: default launch bounds target 8 waves/EU -> 64-VGPR cap;
// the widened kq/pre1 unrolls need ~100 VGPRs -> every hot-loop temp went to
// scratch (36 GB WRITE_SIZE, 19 GB FETCH_SIZE, VALUBusy 57->20). Occupancy is
// LDS-bound at 1 block/CU (= 4 waves/SIMD), so min-waves=4 raises the VGPR
// cap to 128 at zero occupancy cost.

__global__ __launch_bounds__(1024, 4)
void literal_kernel(const float* __restrict__ in0,
                    const float* __restrict__ emb,
                    const float* __restrict__ wk11, const float* __restrict__ wq11,
                    const float* __restrict__ wv11,
                    const float* __restrict__ wk12, const float* __restrict__ wq12,
                    const float* __restrict__ wv12,
                    const float* __restrict__ l1,
                    const float* __restrict__ wk21, const float* __restrict__ wq21,
                    const float* __restrict__ wv21,
                    const float* __restrict__ wk22, const float* __restrict__ wq22,
                    const float* __restrict__ wv22,
                    const float* __restrict__ l2,
                    const float* __restrict__ L3, const float* __restrict__ L4,
                    float* __restrict__ out)
{
    __shared__ float xsh[66];
    __shared__ float ysh[128 * 65];                 // y[j][s]; later y2[h][s]
    __shared__ __align__(16) float kTsh[65 * 132];  // kT[s][i]; att[s*128+i]; q2T[t][i]
    __shared__ float qsh[128 * 65];                 // q[i][t]
    __shared__ __align__(16) float vsh[128 * 68];   // v[i][t] / v2[i][t], stride 68
    __shared__ __align__(16) float smsh[65 * 68];   // sm[s][t] stride 68; stage2: psum/l3p
    __shared__ float kq64sh[65];
    __shared__ __align__(16) float k2col[128];
    __shared__ __align__(16) float attr[128];
    __shared__ float lshf[66];
    __shared__ __align__(16) float smr[68];
    __shared__ float y4sh[128];

    const int tid  = threadIdx.x;
    const int lane = tid & 63;
    const int wu   = __builtin_amdgcn_readfirstlane(tid >> 6);   // wave 0..15
    const long b   = blockIdx.x;

    if (tid < 64) xsh[tid] = in0[b * 64 + tid];
    if (tid == 64) xsh[64] = 1.0f;
    __syncthreads();

    // y[j][s] = emb[j][s] * x[s]
    for (int idx = tid; idx < 8320; idx += 1024) {
        int s = idx % 65;
        ysh[idx] = emb[idx] * xsh[s];
    }
    __syncthreads();

    // pre1 accumulators: thread owns h = 4*(tid&31)..+3, s = (tid>>5) + 32*si
    const int h4 = (tid & 31) * 4;
    const int sb = tid >> 5;            // 0..31
    float4 acc1[3];
    acc1[0] = make_float4(0.f, 0.f, 0.f, 0.f);
    acc1[1] = make_float4(0.f, 0.f, 0.f, 0.f);
    acc1[2] = make_float4(0.f, 0.f, 0.f, 0.f);

    float* attsh = kTsh;   // att[s*128+i] overwrites kT after kq

    for (int a = 0; a < 2; ++a) {
        const float* wk = a ? wk12 : wk11;
        const float* wq = a ? wq12 : wq11;
        const float* wv = a ? wv12 : wv11;

        // ---- projections: wave wu computes rows i = wu*8 + r, lanes = col s ----
        {
            float aK[8], aQ[8], aV[8];
            #pragma unroll
            for (int r = 0; r < 8; ++r) { aK[r] = aQ[r] = aV[r] = 0.f; }
            float acc64 = 0.f;                       // col-64 side chain (24 lanes)
            const int i0 = wu * 8;
            const int ch = lane >> 3;                // 0:K 1:Q 2:V for lane<24
            const float* Wc = (ch == 0) ? wk : ((ch == 1) ? wq : wv);
            const float* wcrow = Wc + (i0 + (lane & 7)) * 128;

            for (int jb = 0; jb < 16; ++jb) {
                float yv[8], y64v[8];
                #pragma unroll
                for (int u = 0; u < 8; ++u) {
                    yv[u]   = ysh[(jb * 8 + u) * 65 + lane];
                    y64v[u] = ysh[(jb * 8 + u) * 65 + 64];
                }
                #pragma unroll
                for (int r = 0; r < 8; ++r) {
                    const float* wkr = wk + (i0 + r) * 128 + jb * 8;
                    const float* wqr = wq + (i0 + r) * 128 + jb * 8;
                    const float* wvr = wv + (i0 + r) * 128 + jb * 8;
                    #pragma unroll
                    for (int u = 0; u < 8; ++u) {
                        aK[r] = fmaf(wkr[u], yv[u], aK[r]);
                        aQ[r] = fmaf(wqr[u], yv[u], aQ[r]);
                        aV[r] = fmaf(wvr[u], yv[u], aV[r]);
                    }
                }
                if (lane < 24) {
                    float4 c0 = *(const float4*)&wcrow[jb * 8];
                    float4 c1 = *(const float4*)&wcrow[jb * 8 + 4];
                    acc64 = fmaf(c0.x, y64v[0], acc64);
                    acc64 = fmaf(c0.y, y64v[1], acc64);
                    acc64 = fmaf(c0.z, y64v[2], acc64);
                    acc64 = fmaf(c0.w, y64v[3], acc64);
                    acc64 = fmaf(c1.x, y64v[4], acc64);
                    acc64 = fmaf(c1.y, y64v[5], acc64);
                    acc64 = fmaf(c1.z, y64v[6], acc64);
                    acc64 = fmaf(c1.w, y64v[7], acc64);
                }
            }
            #pragma unroll
            for (int r = 0; r < 8; ++r) {
                int i = i0 + r;
                kTsh[lane * 132 + i] = aK[r];        // transposed
                qsh[i * 65 + lane] = aQ[r];
                vsh[i * 68 + lane] = aV[r];
            }
            if (lane < 8)       kTsh[64 * 132 + i0 + lane]       = acc64;
            else if (lane < 16) qsh[(i0 + (lane & 7)) * 65 + 64] = acc64;
            else if (lane < 24) vsh[(i0 + (lane & 7)) * 68 + 64] = acc64;
        }
        __syncthreads();

        // ---- kq: wave wu owns rows s = 4*wu + rr (wave 15 also s=64) ----
        float kqa[5];
        kqa[0] = kqa[1] = kqa[2] = kqa[3] = kqa[4] = 0.f;
        if (tid < 65) {                       // column t = 64 (exact chain)
            float acc = 0.f;
            const float* kr = &kTsh[tid * 132];
            for (int i0b = 0; i0b < 128; i0b += 4) {
                float4 kk = *(const float4*)&kr[i0b];
                acc = fmaf(kk.x, qsh[(i0b + 0) * 65 + 64], acc);
                acc = fmaf(kk.y, qsh[(i0b + 1) * 65 + 64], acc);
                acc = fmaf(kk.z, qsh[(i0b + 2) * 65 + 64], acc);
                acc = fmaf(kk.w, qsh[(i0b + 3) * 65 + 64], acc);
            }
            kq64sh[tid] = acc;
        }
        {
            const int sbase = 4 * wu;
            for (int i0b = 0; i0b < 128; i0b += 4) {
                float4 k0 = *(const float4*)&kTsh[(sbase + 0) * 132 + i0b];
                float4 k1 = *(const float4*)&kTsh[(sbase + 1) * 132 + i0b];
                float4 k2 = *(const float4*)&kTsh[(sbase + 2) * 132 + i0b];
                float4 k3 = *(const float4*)&kTsh[(sbase + 3) * 132 + i0b];
                float q0 = qsh[(i0b + 0) * 65 + lane];
                float q1 = qsh[(i0b + 1) * 65 + lane];
                float q2v = qsh[(i0b + 2) * 65 + lane];
                float q3v = qsh[(i0b + 3) * 65 + lane];
                kqa[0] = fmaf(k0.x, q0, kqa[0]); kqa[0] = fmaf(k0.y, q1, kqa[0]);
                kqa[0] = fmaf(k0.z, q2v, kqa[0]); kqa[0] = fmaf(k0.w, q3v, kqa[0]);
                kqa[1] = fmaf(k1.x, q0, kqa[1]); kqa[1] = fmaf(k1.y, q1, kqa[1]);
                kqa[1] = fmaf(k1.z, q2v, kqa[1]); kqa[1] = fmaf(k1.w, q3v, kqa[1]);
                kqa[2] = fmaf(k2.x, q0, kqa[2]); kqa[2] = fmaf(k2.y, q1, kqa[2]);
                kqa[2] = fmaf(k2.z, q2v, kqa[2]); kqa[2] = fmaf(k2.w, q3v, kqa[2]);
                kqa[3] = fmaf(k3.x, q0, kqa[3]); kqa[3] = fmaf(k3.y, q1, kqa[3]);
                kqa[3] = fmaf(k3.z, q2v, kqa[3]); kqa[3] = fmaf(k3.w, q3v, kqa[3]);
                if (wu == 15) {
                    float4 k4 = *(const float4*)&kTsh[64 * 132 + i0b];
                    kqa[4] = fmaf(k4.x, q0, kqa[4]); kqa[4] = fmaf(k4.y, q1, kqa[4]);
                    kqa[4] = fmaf(k4.z, q2v, kqa[4]); kqa[4] = fmaf(k4.w, q3v, kqa[4]);
                }
            }
        }
        __syncthreads();

        // ---- softmax over t, rows in registers (same butterfly DAG) ----
        #pragma unroll
        for (int rr = 0; rr < 5; ++rr) {
            if (rr < 4 || wu == 15) {
                int s = (rr == 4) ? 64 : 4 * wu + rr;
                float lg   = kqa[rr];
                float l64v = (lane == 0) ? kq64sh[s] : -3.0e38f;
                float mm = fmaxf(lg, l64v);
                #pragma unroll
                for (int off = 32; off >= 1; off >>= 1) mm = fmaxf(mm, __shfl_xor(mm, off));
                float e   = expf(lg - mm);
                float e64 = (lane == 0) ? expf(l64v - mm) : 0.f;
                float zs = e + e64;
                #pragma unroll
                for (int off = 32; off >= 1; off >>= 1) zs += __shfl_xor(zs, off);
                float inv = 1.0f / zs;
                smsh[s * 68 + lane] = e * inv;
                if (lane == 0) smsh[s * 68 + 64] = e64 * inv;
            }
        }
        __syncthreads();

        // ---- att[s][i] = sum_t sm[s][t]*v[i][t]; float4 along t ----
        {
            const int iA = tid & 127;
            const int sg = tid >> 7;           // 0..7, uniform per wave
            float aa[9];
            #pragma unroll
            for (int m = 0; m < 9; ++m) aa[m] = 0.f;
            for (int k = 0; k < 16; ++k) {
                float4 vq = *(const float4*)&vsh[iA * 68 + 4 * k];
                #pragma unroll
                for (int m = 0; m < 9; ++m) {
                    if (m < 8 || sg == 0) {
                        int s = sg + 8 * m;
                        float4 sq = *(const float4*)&smsh[s * 68 + 4 * k];
                        aa[m] = fmaf(sq.x, vq.x, aa[m]);
                        aa[m] = fmaf(sq.y, vq.y, aa[m]);
                        aa[m] = fmaf(sq.z, vq.z, aa[m]);
                        aa[m] = fmaf(sq.w, vq.w, aa[m]);
                    }
                }
            }
            float v64 = vsh[iA * 68 + 64];
            #pragma unroll
            for (int m = 0; m < 9; ++m) {
                if (m < 8 || sg == 0) {
                    int s = sg + 8 * m;
                    aa[m] = fmaf(smsh[s * 68 + 64], v64, aa[m]);
                    attsh[s * 128 + iA] = aa[m];
                }
            }
        }
        __syncthreads();

        // ---- pre1[s][h] += sum_i att[s][i]*l1a[i][h]  (b128 att broadcasts) ----
        {
            const float* l1a = l1 + a * (128 * 128);
            for (int i0b = 0; i0b < 128; i0b += 4) {
                float4 lv0 = *(const float4*)&l1a[(i0b + 0) * 128 + h4];
                float4 lv1 = *(const float4*)&l1a[(i0b + 1) * 128 + h4];
                float4 lv2 = *(const float4*)&l1a[(i0b + 2) * 128 + h4];
                float4 lv3 = *(const float4*)&l1a[(i0b + 3) * 128 + h4];
                #pragma unroll
                for (int si = 0; si < 3; ++si) {
                    if (si < 2 || sb == 0) {
                        int s = sb + 32 * si;
                        float4 av = *(const float4*)&attsh[s * 128 + i0b];
                        float4 acc = acc1[si];
                        acc.x = fmaf(av.x, lv0.x, acc.x); acc.x = fmaf(av.y, lv1.x, acc.x);
                        acc.x = fmaf(av.z, lv2.x, acc.x); acc.x = fmaf(av.w, lv3.x, acc.x);
                        acc.y = fmaf(av.x, lv0.y, acc.y); acc.y = fmaf(av.y, lv1.y, acc.y);
                        acc.y = fmaf(av.z, lv2.y, acc.y); acc.y = fmaf(av.w, lv3.y, acc.y);
                        acc.z = fmaf(av.x, lv0.z, acc.z); acc.z = fmaf(av.y, lv1.z, acc.z);
                        acc.z = fmaf(av.z, lv2.z, acc.z); acc.z = fmaf(av.w, lv3.z, acc.z);
                        acc.w = fmaf(av.x, lv0.w, acc.w); acc.w = fmaf(av.y, lv1.w, acc.w);
                        acc.w = fmaf(av.z, lv2.w, acc.w); acc.w = fmaf(av.w, lv3.w, acc.w);
                        acc1[si] = acc;
                    }
                }
            }
        }
        __syncthreads();
    }

    // ---- y2[h][s] = tanh(pre1[s][h])  (into ysh region, stride 65) ----
    float* y2sh = ysh;
    #pragma unroll
    for (int si = 0; si < 3; ++si) {
        if (si < 2 || sb == 0) {
            int s = sb + 32 * si;
            y2sh[(h4 + 0) * 65 + s] = tanhf(acc1[si].x);
            y2sh[(h4 + 1) * 65 + s] = tanhf(acc1[si].y);
            y2sh[(h4 + 2) * 65 + s] = tanhf(acc1[si].z);
            y2sh[(h4 + 3) * 65 + s] = tanhf(acc1[si].w);
        }
    }
    __syncthreads();

    // ---- stage 2 (literal; only row s=64 used downstream) ----
    float* q2Tsh = kTsh;        // q2T[t][i], stride 132
    float* v2sh  = vsh;         // stride 68
    float* psum  = smsh;        // stage-2 scratch (sm dead)
    float pre2 = 0.f;           // valid for tid < 128

    for (int a2 = 0; a2 < 2; ++a2) {
        const float* wk2 = a2 ? wk22 : wk21;
        const float* wq2 = a2 ? wq22 : wq21;
        const float* wv2 = a2 ? wv22 : wv21;

        {
            float aQ[8], aV[8];
            #pragma unroll
            for (int r = 0; r < 8; ++r) { aQ[r] = aV[r] = 0.f; }
            float acc64 = 0.f;               // 0..7: q2 col64, 8..15: v2 col64, 16..23: k2col
            const int i0 = wu * 8;
            const int ch = lane >> 3;
            const float* Wc = (ch == 0) ? wq2 : ((ch == 1) ? wv2 : wk2);
            const float* wcrow = Wc + (i0 + (lane & 7)) * 128;

            for (int jb = 0; jb < 16; ++jb) {
                float yv[8], y64v[8];
                #pragma unroll
                for (int u = 0; u < 8; ++u) {
                    yv[u]   = y2sh[(jb * 8 + u) * 65 + lane];
                    y64v[u] = y2sh[(jb * 8 + u) * 65 + 64];
                }
                #pragma unroll
                for (int r = 0; r < 8; ++r) {
                    const float* wqr = wq2 + (i0 + r) * 128 + jb * 8;
                    const float* wvr = wv2 + (i0 + r) * 128 + jb * 8;
                    #pragma unroll
                    for (int u = 0; u < 8; ++u) {
                        aQ[r] = fmaf(wqr[u], yv[u], aQ[r]);
                        aV[r] = fmaf(wvr[u], yv[u], aV[r]);
                    }
                }
                if (lane < 24) {
                    float4 c0 = *(const float4*)&wcrow[jb * 8];
                    float4 c1 = *(const float4*)&wcrow[jb * 8 + 4];
                    acc64 = fmaf(c0.x, y64v[0], acc64);
                    acc64 = fmaf(c0.y, y64v[1], acc64);
                    acc64 = fmaf(c0.z, y64v[2], acc64);
                    acc64 = fmaf(c0.w, y64v[3], acc64);
                    acc64 = fmaf(c1.x, y64v[4], acc64);
                    acc64 = fmaf(c1.y, y64v[5], acc64);
                    acc64 = fmaf(c1.z, y64v[6], acc64);
                    acc64 = fmaf(c1.w, y64v[7], acc64);
                }
            }
            #pragma unroll
            for (int r = 0; r < 8; ++r) {
                int i = i0 + r;
                q2Tsh[lane * 132 + i] = aQ[r];       // transposed
                v2sh[i * 68 + lane] = aV[r];
            }
            if (lane < 8)       q2Tsh[64 * 132 + i0 + lane]      = acc64;
            else if (lane < 16) v2sh[(i0 + (lane & 7)) * 68 + 64] = acc64;
            else if (lane < 24) k2col[i0 + (lane & 7)]            = acc64;
        }
        __syncthreads();

        // kq2[64][t] = sum_i k2col[i]*q2[i][t]  (exact i-ascending chain)
        if (tid < 65) {
            float acc = 0.f;
            const float* qr = &q2Tsh[tid * 132];
            for (int i0b = 0; i0b < 128; i0b += 4) {
                float4 qq = *(const float4*)&qr[i0b];
                float4 kc = *(const float4*)&k2col[i0b];
                acc = fmaf(kc.x, qq.x, acc);
                acc = fmaf(kc.y, qq.y, acc);
                acc = fmaf(kc.z, qq.z, acc);
                acc = fmaf(kc.w, qq.w, acc);
            }
            lshf[tid] = acc;
        }
        __syncthreads();

        if (tid < 64) {
            float lg   = lshf[lane];
            float l64v = (lane == 0) ? lshf[64] : -3.0e38f;
            float mm = fmaxf(lg, l64v);
            #pragma unroll
            for (int off = 32; off >= 1; off >>= 1) mm = fmaxf(mm, __shfl_xor(mm, off));
            float e   = expf(lg - mm);
            float e64 = (lane == 0) ? expf(l64v - mm) : 0.f;
            float zs = e + e64;
            #pragma unroll
            for (int off = 32; off >= 1; off >>= 1) zs += __shfl_xor(zs, off);
            float inv = 1.0f / zs;
            smr[lane] = e * inv;
            if (lane == 0) smr[64] = e64 * inv;
        }
        __syncthreads();

        // att2[64][i] = sum_t sm2[t]*v2[i][t]  (exact t-ascending chain)
        if (tid < 128) {
            float acc = 0.f;
            const float* vr = &v2sh[tid * 68];
            for (int k = 0; k < 16; ++k) {
                float4 sq = *(const float4*)&smr[4 * k];
                float4 vq = *(const float4*)&vr[4 * k];
                acc = fmaf(sq.x, vq.x, acc);
                acc = fmaf(sq.y, vq.y, acc);
                acc = fmaf(sq.z, vq.z, acc);
                acc = fmaf(sq.w, vq.w, acc);
            }
            acc = fmaf(smr[64], vr[64], acc);
            attr[tid] = acc;
        }
        __syncthreads();

        // pre2[h] += sum_i att2[i]*l2a[i][h]  (split-K over 8 chunks, post-softmax)
        {
            const int hh = tid & 127, cc = tid >> 7;
            const float* l2a = l2 + a2 * (128 * 128);
            float p = 0.f;
            #pragma unroll
            for (int g = 0; g < 4; ++g) {
                int i = cc * 16 + 4 * g;
                float4 av = *(const float4*)&attr[i];
                p = fmaf(av.x, l2a[(i + 0) * 128 + hh], p);
                p = fmaf(av.y, l2a[(i + 1) * 128 + hh], p);
                p = fmaf(av.z, l2a[(i + 2) * 128 + hh], p);
                p = fmaf(av.w, l2a[(i + 3) * 128 + hh], p);
            }
            psum[cc * 128 + hh] = p;
        }
        __syncthreads();
        if (tid < 128) {
            float red = psum[tid];
            #pragma unroll
            for (int c = 1; c < 8; ++c) red += psum[c * 128 + tid];
            pre2 += red;
        }
        // no barrier needed: psum not rewritten until after next a2's att2 sync
    }

    if (tid < 128) y4sh[tid] = tanhf(pre2);
    __syncthreads();

    // t3[o] = sum_h y4[h]*L3[h][o]  (split-K over 16 chunks, post-softmax)
    {
        float* l3p = smsh + 1024;
        const int oo = tid & 63, cc = tid >> 6;   // cc 0..15
        float p = 0.f;
        #pragma unroll
        for (int u = 0; u < 8; ++u) {
            int h = cc * 8 + u;
            p = fmaf(y4sh[h], L3[h * 64 + oo], p);
        }
        l3p[cc * 64 + oo] = p;
    }
    __syncthreads();
    if (tid < 64) {
        float* l3p = smsh + 1024;
        float t3 = l3p[tid];
        #pragma unroll
        for (int c = 1; c < 16; ++c) t3 += l3p[c * 64 + tid];
        float y5 = tanhf(t3);
        float sc = y5 * L4[tid];
        #pragma unroll
        for (int off = 32; off >= 1; off >>= 1) sc += __shfl_xor(sc, off);
        if (tid == 0) out[b] = sc;
    }
}

extern "C" void kernel_launch(void* const* d_in, const int* in_sizes, int n_in,
                              void* d_out, int out_size, void* d_ws, size_t ws_size,
                              hipStream_t stream) {
    const float* in0  = (const float*)d_in[0];
    const float* emb  = (const float*)d_in[1];
    const float* wk11 = (const float*)d_in[2];
    const float* wq11 = (const float*)d_in[3];
    const float* wv11 = (const float*)d_in[4];
    const float* wk12 = (const float*)d_in[5];
    const float* wq12 = (const float*)d_in[6];
    const float* wv12 = (const float*)d_in[7];
    const float* l1   = (const float*)d_in[8];
    const float* wk21 = (const float*)d_in[9];
    const float* wq21 = (const float*)d_in[10];
    const float* wv21 = (const float*)d_in[11];
    const float* wk22 = (const float*)d_in[12];
    const float* wq22 = (const float*)d_in[13];
    const float* wv22 = (const float*)d_in[14];
    const float* l2   = (const float*)d_in[15];
    const float* l3   = (const float*)d_in[16];
    const float* l4   = (const float*)d_in[17];
    float* out = (float*)d_out;

    int B = in_sizes[0] / 64;   // 8192

    literal_kernel<<<B, 1024, 0, stream>>>(in0, emb,
                                           wk11, wq11, wv11, wk12, wq12, wv12, l1,
                                           wk21, wq21, wv21, wk22, wq22, wv22, l2,
                                           l3, l4, out);
}

// Round 5
// 7736.110 us; speedup vs baseline: 3.1327x; 3.1298x over previous
//
#include <hip/hip_runtime.h>
#include <math.h>

// Round 5 = round 3 dataflow (DAG-identical everywhere), with the register
// pressure of the two widened loops cut back so the kernel fits a 64-VGPR
// budget even if the occupancy attributes are ignored:
//  - kq: q0..q3 loaded once, k rows walked SEQUENTIALLY (1 float4 live, not 4)
//  - pre1: att float4s loaded first, l1 rows walked SEQUENTIALLY
// plus direct clang attributes (amdgpu_flat_work_group_size + waves_per_eu)
// since __launch_bounds__(1024,4) was demonstrably a no-op (round 4 ==
// round 3 byte-for-byte in dur/VGPR/spill counters).

__global__
__attribute__((amdgpu_flat_work_group_size(1024, 1024)))
__attribute__((amdgpu_waves_per_eu(4, 4)))
void literal_kernel(const float* __restrict__ in0,
                    const float* __restrict__ emb,
                    const float* __restrict__ wk11, const float* __restrict__ wq11,
                    const float* __restrict__ wv11,
                    const float* __restrict__ wk12, const float* __restrict__ wq12,
                    const float* __restrict__ wv12,
                    const float* __restrict__ l1,
                    const float* __restrict__ wk21, const float* __restrict__ wq21,
                    const float* __restrict__ wv21,
                    const float* __restrict__ wk22, const float* __restrict__ wq22,
                    const float* __restrict__ wv22,
                    const float* __restrict__ l2,
                    const float* __restrict__ L3, const float* __restrict__ L4,
                    float* __restrict__ out)
{
    __shared__ float xsh[66];
    __shared__ float ysh[128 * 65];                 // y[j][s]; later y2[h][s]
    __shared__ __align__(16) float kTsh[65 * 132];  // kT[s][i]; att[s*128+i]; q2T[t][i]
    __shared__ float qsh[128 * 65];                 // q[i][t]
    __shared__ __align__(16) float vsh[128 * 68];   // v[i][t] / v2[i][t], stride 68
    __shared__ __align__(16) float smsh[65 * 68];   // sm[s][t] stride 68; stage2 scratch
    __shared__ float kq64sh[65];
    __shared__ __align__(16) float k2col[128];
    __shared__ __align__(16) float attr[128];
    __shared__ float lshf[66];
    __shared__ __align__(16) float smr[68];
    __shared__ float y4sh[128];

    const int tid  = threadIdx.x;
    const int lane = tid & 63;
    const int wu   = __builtin_amdgcn_readfirstlane(tid >> 6);   // wave 0..15
    const long b   = blockIdx.x;

    if (tid < 64) xsh[tid] = in0[b * 64 + tid];
    if (tid == 64) xsh[64] = 1.0f;
    __syncthreads();

    // y[j][s] = emb[j][s] * x[s]
    for (int idx = tid; idx < 8320; idx += 1024) {
        int s = idx % 65;
        ysh[idx] = emb[idx] * xsh[s];
    }
    __syncthreads();

    // pre1 accumulators: thread owns h = 4*(tid&31)..+3, s = (tid>>5) + 32*si
    const int h4 = (tid & 31) * 4;
    const int sb = tid >> 5;            // 0..31
    float4 acc1[3];
    acc1[0] = make_float4(0.f, 0.f, 0.f, 0.f);
    acc1[1] = make_float4(0.f, 0.f, 0.f, 0.f);
    acc1[2] = make_float4(0.f, 0.f, 0.f, 0.f);

    float* attsh = kTsh;   // att[s*128+i] overwrites kT after kq

    for (int a = 0; a < 2; ++a) {
        const float* wk = a ? wk12 : wk11;
        const float* wq = a ? wq12 : wq11;
        const float* wv = a ? wv12 : wv11;

        // ---- projections: wave wu computes rows i = wu*8 + r, lanes = col s ----
        {
            float aK[8], aQ[8], aV[8];
            #pragma unroll
            for (int r = 0; r < 8; ++r) { aK[r] = aQ[r] = aV[r] = 0.f; }
            float acc64 = 0.f;                       // col-64 side chain (24 lanes)
            const int i0 = wu * 8;
            const int ch = lane >> 3;                // 0:K 1:Q 2:V for lane<24
            const float* Wc = (ch == 0) ? wk : ((ch == 1) ? wq : wv);
            const float* wcrow = Wc + (i0 + (lane & 7)) * 128;

            for (int jb = 0; jb < 16; ++jb) {
                float yv[8], y64v[8];
                #pragma unroll
                for (int u = 0; u < 8; ++u) {
                    yv[u]   = ysh[(jb * 8 + u) * 65 + lane];
                    y64v[u] = ysh[(jb * 8 + u) * 65 + 64];
                }
                #pragma unroll
                for (int r = 0; r < 8; ++r) {
                    const float* wkr = wk + (i0 + r) * 128 + jb * 8;
                    const float* wqr = wq + (i0 + r) * 128 + jb * 8;
                    const float* wvr = wv + (i0 + r) * 128 + jb * 8;
                    #pragma unroll
                    for (int u = 0; u < 8; ++u) {
                        aK[r] = fmaf(wkr[u], yv[u], aK[r]);
                        aQ[r] = fmaf(wqr[u], yv[u], aQ[r]);
                        aV[r] = fmaf(wvr[u], yv[u], aV[r]);
                    }
                }
                if (lane < 24) {
                    float4 c0 = *(const float4*)&wcrow[jb * 8];
                    float4 c1 = *(const float4*)&wcrow[jb * 8 + 4];
                    acc64 = fmaf(c0.x, y64v[0], acc64);
                    acc64 = fmaf(c0.y, y64v[1], acc64);
                    acc64 = fmaf(c0.z, y64v[2], acc64);
                    acc64 = fmaf(c0.w, y64v[3], acc64);
                    acc64 = fmaf(c1.x, y64v[4], acc64);
                    acc64 = fmaf(c1.y, y64v[5], acc64);
                    acc64 = fmaf(c1.z, y64v[6], acc64);
                    acc64 = fmaf(c1.w, y64v[7], acc64);
                }
            }
            #pragma unroll
            for (int r = 0; r < 8; ++r) {
                int i = i0 + r;
                kTsh[lane * 132 + i] = aK[r];        // transposed
                qsh[i * 65 + lane] = aQ[r];
                vsh[i * 68 + lane] = aV[r];
            }
            if (lane < 8)       kTsh[64 * 132 + i0 + lane]       = acc64;
            else if (lane < 16) qsh[(i0 + (lane & 7)) * 65 + 64] = acc64;
            else if (lane < 24) vsh[(i0 + (lane & 7)) * 68 + 64] = acc64;
        }
        __syncthreads();

        // ---- kq: wave wu owns rows s = 4*wu + rr (wave 15 also s=64) ----
        float kqa[5];
        kqa[0] = kqa[1] = kqa[2] = kqa[3] = kqa[4] = 0.f;
        if (tid < 65) {                       // column t = 64 (exact chain)
            float acc = 0.f;
            const float* kr = &kTsh[tid * 132];
            for (int i0b = 0; i0b < 128; i0b += 4) {
                float4 kk = *(const float4*)&kr[i0b];
                acc = fmaf(kk.x, qsh[(i0b + 0) * 65 + 64], acc);
                acc = fmaf(kk.y, qsh[(i0b + 1) * 65 + 64], acc);
                acc = fmaf(kk.z, qsh[(i0b + 2) * 65 + 64], acc);
                acc = fmaf(kk.w, qsh[(i0b + 3) * 65 + 64], acc);
            }
            kq64sh[tid] = acc;
        }
        {
            const int sbase = 4 * wu;
            for (int i0b = 0; i0b < 128; i0b += 4) {
                float q0  = qsh[(i0b + 0) * 65 + lane];
                float q1  = qsh[(i0b + 1) * 65 + lane];
                float q2v = qsh[(i0b + 2) * 65 + lane];
                float q3v = qsh[(i0b + 3) * 65 + lane];
                // walk k rows sequentially: one float4 live at a time
                #pragma unroll
                for (int r = 0; r < 4; ++r) {
                    float4 kk = *(const float4*)&kTsh[(sbase + r) * 132 + i0b];
                    kqa[r] = fmaf(kk.x, q0,  kqa[r]);
                    kqa[r] = fmaf(kk.y, q1,  kqa[r]);
                    kqa[r] = fmaf(kk.z, q2v, kqa[r]);
                    kqa[r] = fmaf(kk.w, q3v, kqa[r]);
                }
                if (wu == 15) {
                    float4 k4 = *(const float4*)&kTsh[64 * 132 + i0b];
                    kqa[4] = fmaf(k4.x, q0,  kqa[4]);
                    kqa[4] = fmaf(k4.y, q1,  kqa[4]);
                    kqa[4] = fmaf(k4.z, q2v, kqa[4]);
                    kqa[4] = fmaf(k4.w, q3v, kqa[4]);
                }
            }
        }
        __syncthreads();

        // ---- softmax over t, rows in registers (same butterfly DAG) ----
        #pragma unroll
        for (int rr = 0; rr < 5; ++rr) {
            if (rr < 4 || wu == 15) {
                int s = (rr == 4) ? 64 : 4 * wu + rr;
                float lg   = kqa[rr];
                float l64v = (lane == 0) ? kq64sh[s] : -3.0e38f;
                float mm = fmaxf(lg, l64v);
                #pragma unroll
                for (int off = 32; off >= 1; off >>= 1) mm = fmaxf(mm, __shfl_xor(mm, off));
                float e   = expf(lg - mm);
                float e64 = (lane == 0) ? expf(l64v - mm) : 0.f;
                float zs = e + e64;
                #pragma unroll
                for (int off = 32; off >= 1; off >>= 1) zs += __shfl_xor(zs, off);
                float inv = 1.0f / zs;
                smsh[s * 68 + lane] = e * inv;
                if (lane == 0) smsh[s * 68 + 64] = e64 * inv;
            }
        }
        __syncthreads();

        // ---- att[s][i] = sum_t sm[s][t]*v[i][t]; float4 along t ----
        {
            const int iA = tid & 127;
            const int sg = tid >> 7;           // 0..7, uniform per wave
            float aa[9];
            #pragma unroll
            for (int m = 0; m < 9; ++m) aa[m] = 0.f;
            for (int k = 0; k < 16; ++k) {
                float4 vq = *(const float4*)&vsh[iA * 68 + 4 * k];
                #pragma unroll
                for (int m = 0; m < 9; ++m) {
                    if (m < 8 || sg == 0) {
                        int s = sg + 8 * m;
                        float4 sq = *(const float4*)&smsh[s * 68 + 4 * k];
                        aa[m] = fmaf(sq.x, vq.x, aa[m]);
                        aa[m] = fmaf(sq.y, vq.y, aa[m]);
                        aa[m] = fmaf(sq.z, vq.z, aa[m]);
                        aa[m] = fmaf(sq.w, vq.w, aa[m]);
                    }
                }
            }
            float v64 = vsh[iA * 68 + 64];
            #pragma unroll
            for (int m = 0; m < 9; ++m) {
                if (m < 8 || sg == 0) {
                    int s = sg + 8 * m;
                    aa[m] = fmaf(smsh[s * 68 + 64], v64, aa[m]);
                    attsh[s * 128 + iA] = aa[m];
                }
            }
        }
        __syncthreads();

        // ---- pre1[s][h] += sum_i att[s][i]*l1a[i][h] ----
        // att float4s loaded first (scalarized), l1 rows walked sequentially:
        // per-component accumulation order stays i-ascending (DAG-identical).
        {
            const float* l1a = l1 + a * (128 * 128);
            for (int i0b = 0; i0b < 128; i0b += 4) {
                float4 av0 = *(const float4*)&attsh[(sb +  0) * 128 + i0b];
                float4 av1 = *(const float4*)&attsh[(sb + 32) * 128 + i0b];
                float4 av2 = make_float4(0.f, 0.f, 0.f, 0.f);
                if (sb == 0) av2 = *(const float4*)&attsh[64 * 128 + i0b];
                float a0[4] = { av0.x, av0.y, av0.z, av0.w };
                float a1[4] = { av1.x, av1.y, av1.z, av1.w };
                float a2[4] = { av2.x, av2.y, av2.z, av2.w };
                #pragma unroll
                for (int r = 0; r < 4; ++r) {
                    float4 lv = *(const float4*)&l1a[(i0b + r) * 128 + h4];
                    acc1[0].x = fmaf(a0[r], lv.x, acc1[0].x);
                    acc1[0].y = fmaf(a0[r], lv.y, acc1[0].y);
                    acc1[0].z = fmaf(a0[r], lv.z, acc1[0].z);
                    acc1[0].w = fmaf(a0[r], lv.w, acc1[0].w);
                    acc1[1].x = fmaf(a1[r], lv.x, acc1[1].x);
                    acc1[1].y = fmaf(a1[r], lv.y, acc1[1].y);
                    acc1[1].z = fmaf(a1[r], lv.z, acc1[1].z);
                    acc1[1].w = fmaf(a1[r], lv.w, acc1[1].w);
                    if (sb == 0) {
                        acc1[2].x = fmaf(a2[r], lv.x, acc1[2].x);
                        acc1[2].y = fmaf(a2[r], lv.y, acc1[2].y);
                        acc1[2].z = fmaf(a2[r], lv.z, acc1[2].z);
                        acc1[2].w = fmaf(a2[r], lv.w, acc1[2].w);
                    }
                }
            }
        }
        __syncthreads();
    }

    // ---- y2[h][s] = tanh(pre1[s][h])  (into ysh region, stride 65) ----
    float* y2sh = ysh;
    #pragma unroll
    for (int si = 0; si < 3; ++si) {
        if (si < 2 || sb == 0) {
            int s = sb + 32 * si;
            y2sh[(h4 + 0) * 65 + s] = tanhf(si == 0 ? acc1[0].x : si == 1 ? acc1[1].x : acc1[2].x);
            y2sh[(h4 + 1) * 65 + s] = tanhf(si == 0 ? acc1[0].y : si == 1 ? acc1[1].y : acc1[2].y);
            y2sh[(h4 + 2) * 65 + s] = tanhf(si == 0 ? acc1[0].z : si == 1 ? acc1[1].z : acc1[2].z);
            y2sh[(h4 + 3) * 65 + s] = tanhf(si == 0 ? acc1[0].w : si == 1 ? acc1[1].w : acc1[2].w);
        }
    }
    __syncthreads();

    // ---- stage 2 (literal; only row s=64 used downstream) ----
    float* q2Tsh = kTsh;        // q2T[t][i], stride 132
    float* v2sh  = vsh;         // stride 68
    float* psum  = smsh;        // stage-2 scratch (sm dead)
    float pre2 = 0.f;           // valid for tid < 128

    for (int a2 = 0; a2 < 2; ++a2) {
        const float* wk2 = a2 ? wk22 : wk21;
        const float* wq2 = a2 ? wq22 : wq21;
        const float* wv2 = a2 ? wv22 : wv21;

        {
            float aQ[8], aV[8];
            #pragma unroll
            for (int r = 0; r < 8; ++r) { aQ[r] = aV[r] = 0.f; }
            float acc64 = 0.f;               // 0..7: q2 col64, 8..15: v2 col64, 16..23: k2col
            const int i0 = wu * 8;
            const int ch = lane >> 3;
            const float* Wc = (ch == 0) ? wq2 : ((ch == 1) ? wv2 : wk2);
            const float* wcrow = Wc + (i0 + (lane & 7)) * 128;

            for (int jb = 0; jb < 16; ++jb) {
                float yv[8], y64v[8];
                #pragma unroll
                for (int u = 0; u < 8; ++u) {
                    yv[u]   = y2sh[(jb * 8 + u) * 65 + lane];
                    y64v[u] = y2sh[(jb * 8 + u) * 65 + 64];
                }
                #pragma unroll
                for (int r = 0; r < 8; ++r) {
                    const float* wqr = wq2 + (i0 + r) * 128 + jb * 8;
                    const float* wvr = wv2 + (i0 + r) * 128 + jb * 8;
                    #pragma unroll
                    for (int u = 0; u < 8; ++u) {
                        aQ[r] = fmaf(wqr[u], yv[u], aQ[r]);
                        aV[r] = fmaf(wvr[u], yv[u], aV[r]);
                    }
                }
                if (lane < 24) {
                    float4 c0 = *(const float4*)&wcrow[jb * 8];
                    float4 c1 = *(const float4*)&wcrow[jb * 8 + 4];
                    acc64 = fmaf(c0.x, y64v[0], acc64);
                    acc64 = fmaf(c0.y, y64v[1], acc64);
                    acc64 = fmaf(c0.z, y64v[2], acc64);
                    acc64 = fmaf(c0.w, y64v[3], acc64);
                    acc64 = fmaf(c1.x, y64v[4], acc64);
                    acc64 = fmaf(c1.y, y64v[5], acc64);
                    acc64 = fmaf(c1.z, y64v[6], acc64);
                    acc64 = fmaf(c1.w, y64v[7], acc64);
                }
            }
            #pragma unroll
            for (int r = 0; r < 8; ++r) {
                int i = i0 + r;
                q2Tsh[lane * 132 + i] = aQ[r];       // transposed
                v2sh[i * 68 + lane] = aV[r];
            }
            if (lane < 8)       q2Tsh[64 * 132 + i0 + lane]      = acc64;
            else if (lane < 16) v2sh[(i0 + (lane & 7)) * 68 + 64] = acc64;
            else if (lane < 24) k2col[i0 + (lane & 7)]            = acc64;
        }
        __syncthreads();

        // kq2[64][t] = sum_i k2col[i]*q2[i][t]  (exact i-ascending chain)
        if (tid < 65) {
            float acc = 0.f;
            const float* qr = &q2Tsh[tid * 132];
            for (int i0b = 0; i0b < 128; i0b += 4) {
                float4 qq = *(const float4*)&qr[i0b];
                float4 kc = *(const float4*)&k2col[i0b];
                acc = fmaf(kc.x, qq.x, acc);
                acc = fmaf(kc.y, qq.y, acc);
                acc = fmaf(kc.z, qq.z, acc);
                acc = fmaf(kc.w, qq.w, acc);
            }
            lshf[tid] = acc;
        }
        __syncthreads();

        if (tid < 64) {
            float lg   = lshf[lane];
            float l64v = (lane == 0) ? lshf[64] : -3.0e38f;
            float mm = fmaxf(lg, l64v);
            #pragma unroll
            for (int off = 32; off >= 1; off >>= 1) mm = fmaxf(mm, __shfl_xor(mm, off));
            float e   = expf(lg - mm);
            float e64 = (lane == 0) ? expf(l64v - mm) : 0.f;
            float zs = e + e64;
            #pragma unroll
            for (int off = 32; off >= 1; off >>= 1) zs += __shfl_xor(zs, off);
            float inv = 1.0f / zs;
            smr[lane] = e * inv;
            if (lane == 0) smr[64] = e64 * inv;
        }
        __syncthreads();

        // att2[64][i] = sum_t sm2[t]*v2[i][t]  (exact t-ascending chain)
        if (tid < 128) {
            float acc = 0.f;
            const float* vr = &v2sh[tid * 68];
            for (int k = 0; k < 16; ++k) {
                float4 sq = *(const float4*)&smr[4 * k];
                float4 vq = *(const float4*)&vr[4 * k];
                acc = fmaf(sq.x, vq.x, acc);
                acc = fmaf(sq.y, vq.y, acc);
                acc = fmaf(sq.z, vq.z, acc);
                acc = fmaf(sq.w, vq.w, acc);
            }
            acc = fmaf(smr[64], vr[64], acc);
            attr[tid] = acc;
        }
        __syncthreads();

        // pre2[h] += sum_i att2[i]*l2a[i][h]  (split-K over 8 chunks, post-softmax)
        {
            const int hh = tid & 127, cc = tid >> 7;
            const float* l2a = l2 + a2 * (128 * 128);
            float p = 0.f;
            #pragma unroll
            for (int g = 0; g < 4; ++g) {
                int i = cc * 16 + 4 * g;
                float4 av = *(const float4*)&attr[i];
                p = fmaf(av.x, l2a[(i + 0) * 128 + hh], p);
                p = fmaf(av.y, l2a[(i + 1) * 128 + hh], p);
                p = fmaf(av.z, l2a[(i + 2) * 128 + hh], p);
                p = fmaf(av.w, l2a[(i + 3) * 128 + hh], p);
            }
            psum[cc * 128 + hh] = p;
        }
        __syncthreads();
        if (tid < 128) {
            float red = psum[tid];
            #pragma unroll
            for (int c = 1; c < 8; ++c) red += psum[c * 128 + tid];
            pre2 += red;
        }
        // no barrier needed: psum not rewritten until after next a2's att2 sync
    }

    if (tid < 128) y4sh[tid] = tanhf(pre2);
    __syncthreads();

    // t3[o] = sum_h y4[h]*L3[h][o]  (split-K over 16 chunks, post-softmax)
    {
        float* l3p = smsh + 1024;
        const int oo = tid & 63, cc = tid >> 6;   // cc 0..15
        float p = 0.f;
        #pragma unroll
        for (int u = 0; u < 8; ++u) {
            int h = cc * 8 + u;
            p = fmaf(y4sh[h], L3[h * 64 + oo], p);
        }
        l3p[cc * 64 + oo] = p;
    }
    __syncthreads();
    if (tid < 64) {
        float* l3p = smsh + 1024;
        float t3 = l3p[tid];
        #pragma unroll
        for (int c = 1; c < 16; ++c) t3 += l3p[c * 64 + tid];
        float y5 = tanhf(t3);
        float sc = y5 * L4[tid];
        #pragma unroll
        for (int off = 32; off >= 1; off >>= 1) sc += __shfl_xor(sc, off);
        if (tid == 0) out[b] = sc;
    }
}

extern "C" void kernel_launch(void* const* d_in, const int* in_sizes, int n_in,
                              void* d_out, int out_size, void* d_ws, size_t ws_size,
                              hipStream_t stream) {
    const float* in0  = (const float*)d_in[0];
    const float* emb  = (const float*)d_in[1];
    const float* wk11 = (const float*)d_in[2];
    const float* wq11 = (const float*)d_in[3];
    const float* wv11 = (const float*)d_in[4];
    const float* wk12 = (const float*)d_in[5];
    const float* wq12 = (const float*)d_in[6];
    const float* wv12 = (const float*)d_in[7];
    const float* l1   = (const float*)d_in[8];
    const float* wk21 = (const float*)d_in[9];
    const float* wq21 = (const float*)d_in[10];
    const float* wv21 = (const float*)d_in[11];
    const float* wk22 = (const float*)d_in[12];
    const float* wq22 = (const float*)d_in[13];
    const float* wv22 = (const float*)d_in[14];
    const float* l2   = (const float*)d_in[15];
    const float* l3   = (const float*)d_in[16];
    const float* l4   = (const float*)d_in[17];
    float* out = (float*)d_out;

    int B = in_sizes[0] / 64;   // 8192

    literal_kernel<<<B, 1024, 0, stream>>>(in0, emb,
                                           wk11, wq11, wv11, wk12, wq12, wv12, l1,
                                           wk21, wq21, wv21, wk22, wq22, wv22, l2,
                                           l3, l4, out);
}